// Round 7
// baseline (9199.992 us; speedup 1.0000x reference)
//
#include <hip/hip_runtime.h>
#include <math.h>

// Problem constants
#define SS 256   // encoder seq len
#define BB 256   // batch
#define HH 512   // hidden
#define OO 64    // output dim
#define NSTEP 63 // only outs[:63] are used

// Fast tanh for the SCORE path only: tanh(x) = 1 - 2/(e^{2x}+1).
// abs err ~2e-7 — below fp32 GEMM noise in EW. Recurrence path keeps libm.
__device__ __forceinline__ float fast_tanh(float x) {
    float e = __builtin_amdgcn_exp2f(x * 2.885390081777927f);
    return 1.f - 2.f * __builtin_amdgcn_rcpf(e + 1.f);
}

// ---------------------------------------------------------------------------
// K0: EW = enc @ Wa_bot  (M=65536, K=512, N=512), fp32, 128x128 tile.
// Output relayout: row m = s*256+b  ->  EW[b][s][h]  (contiguous per batch b)
// ---------------------------------------------------------------------------
__global__ __launch_bounds__(256) void k_ew_gemm(const float* __restrict__ A,
                                                 const float* __restrict__ Bm,
                                                 float* __restrict__ C)
{
    __shared__ float As[8][132];
    __shared__ float Bs[8][132];
    const int tid = threadIdx.x;
    const int bm = blockIdx.x * 128;
    const int bn = blockIdx.y * 128;
    const int tx = tid & 15;
    const int ty = tid >> 4;
    const int a_row = tid >> 1;
    const int a_k4 = (tid & 1) * 4;
    const int b_row = tid >> 5;
    const int b_n4 = (tid & 31) * 4;

    float acc[8][8];
#pragma unroll
    for (int i = 0; i < 8; i++)
#pragma unroll
        for (int j = 0; j < 8; j++) acc[i][j] = 0.f;

    for (int kt = 0; kt < 512; kt += 8) {
        float4 av = *(const float4*)(A + (size_t)(bm + a_row) * 512 + kt + a_k4);
        As[a_k4 + 0][a_row] = av.x;
        As[a_k4 + 1][a_row] = av.y;
        As[a_k4 + 2][a_row] = av.z;
        As[a_k4 + 3][a_row] = av.w;
        *(float4*)(&Bs[b_row][b_n4]) = *(const float4*)(Bm + (size_t)(kt + b_row) * 512 + bn + b_n4);
        __syncthreads();
#pragma unroll
        for (int kk = 0; kk < 8; kk++) {
            float av8[8], bv8[8];
            *(float4*)&av8[0] = *(const float4*)&As[kk][ty * 4];
            *(float4*)&av8[4] = *(const float4*)&As[kk][64 + ty * 4];
            *(float4*)&bv8[0] = *(const float4*)&Bs[kk][tx * 4];
            *(float4*)&bv8[4] = *(const float4*)&Bs[kk][64 + tx * 4];
#pragma unroll
            for (int i = 0; i < 8; i++)
#pragma unroll
                for (int j = 0; j < 8; j++) acc[i][j] += av8[i] * bv8[j];
        }
        __syncthreads();
    }
#pragma unroll
    for (int i = 0; i < 8; i++) {
        int m = bm + ((i < 4) ? (ty * 4 + i) : (64 + ty * 4 + i - 4));
        int mrow = (m & 255) * 256 + (m >> 8);   // [b][s] relayout
        float4 o0 = make_float4(acc[i][0], acc[i][1], acc[i][2], acc[i][3]);
        float4 o1 = make_float4(acc[i][4], acc[i][5], acc[i][6], acc[i][7]);
        *(float4*)(C + (size_t)mrow * 512 + bn + tx * 4) = o0;
        *(float4*)(C + (size_t)mrow * 512 + bn + 64 + tx * 4) = o1;
    }
}

// ---------------------------------------------------------------------------
// q init: qpre = h0 @ Wa_top   (no bias; ba deferred to k_attn)
// ---------------------------------------------------------------------------
__global__ __launch_bounds__(256) void k_qinit(const float* __restrict__ A,
                                               const float* __restrict__ Wa,
                                               float* __restrict__ qpre)
{
    __shared__ float As[32][33];
    __shared__ float Bs[32][33];
    const int tid = threadIdx.x;
    const int bn = blockIdx.x * 32;
    const int bm = blockIdx.y * 32;
    const int tx = tid & 15;
    const int ty = tid >> 4;
    const int l_row = tid >> 3;
    const int l_c4 = (tid & 7) * 4;

    float acc00 = 0.f, acc01 = 0.f, acc10 = 0.f, acc11 = 0.f;
    for (int kt = 0; kt < 512; kt += 32) {
#pragma unroll
        for (int i = 0; i < 4; i++)
            As[l_c4 + i][l_row] = A[(size_t)(bm + l_row) * 512 + kt + l_c4 + i];
#pragma unroll
        for (int i = 0; i < 4; i++)
            Bs[l_row][l_c4 + i] = Wa[(size_t)(kt + l_row) * 512 + bn + l_c4 + i];
        __syncthreads();
#pragma unroll
        for (int kk = 0; kk < 32; kk++) {
            float a0 = As[kk][ty * 2], a1 = As[kk][ty * 2 + 1];
            float b0 = Bs[kk][tx * 2], b1 = Bs[kk][tx * 2 + 1];
            acc00 += a0 * b0; acc01 += a0 * b1;
            acc10 += a1 * b0; acc11 += a1 * b1;
        }
        __syncthreads();
    }
    qpre[(size_t)(bm + ty * 2) * 512 + bn + tx * 2]     = acc00;
    qpre[(size_t)(bm + ty * 2) * 512 + bn + tx * 2 + 1] = acc01;
    qpre[(size_t)(bm + ty * 2 + 1) * 512 + bn + tx * 2]     = acc10;
    qpre[(size_t)(bm + ty * 2 + 1) * 512 + bn + tx * 2 + 1] = acc11;
}

// ---------------------------------------------------------------------------
// k_attn: per batch b.
//  - wave 0 (t>0): argmax of prev step's ob[b]+bo -> xb one-hot, dout[t-1].
//  - scores: fast_tanh(EW[b][s]+q[b])·v; softmax over s; context from enc.
// 1024 threads = 16 waves; wave w owns s in [w*16,w*16+16); lane l owns
// h = l*8..l*8+7. 2-way s-unroll (round-2-proven body). No zeroing work.
// ---------------------------------------------------------------------------
__global__ __launch_bounds__(1024) void k_attn(const float* __restrict__ EW,
                                               const float* __restrict__ enc,
                                               const float* __restrict__ qpre,
                                               const float* __restrict__ ba,
                                               const float* __restrict__ vvec,
                                               float* __restrict__ ctx,
                                               const float* __restrict__ ob,
                                               const float* __restrict__ bo,
                                               float* __restrict__ dout,
                                               float* __restrict__ xb,
                                               int t)
{
    __shared__ float qs[512];
    __shared__ float vs[512];
    __shared__ float sc[256];
    __shared__ float red[16];
    __shared__ float ctxp[16][512];
    const int b = blockIdx.x;
    const int tid = threadIdx.x;

    // prev-step argmax + dout write (ob complete from k_outq(t-1))
    if (t > 0 && tid < 64) {
        const int l = tid;
        float v = ob[b * 64 + l] + bo[l];
        dout[(size_t)b * (OO * NSTEP) + l * NSTEP + (t - 1)] = v;
        int bi = l;
        float bv = v;
#pragma unroll
        for (int off = 1; off < 64; off <<= 1) {
            float ov = __shfl_xor(bv, off);
            int oi = __shfl_xor(bi, off);
            if (ov > bv || (ov == bv && oi < bi)) { bv = ov; bi = oi; }
        }
        xb[b * 64 + l] = (l == bi) ? 1.0f : 0.0f;
    }

    if (tid < 512) {
        qs[tid] = qpre[b * 512 + tid] + ba[tid];
        vs[tid] = vvec[tid];
    }
    __syncthreads();

    const int w = tid >> 6;    // 0..15
    const int l = tid & 63;

    float qv[8], vv[8];
    *(float4*)&qv[0] = *(const float4*)&qs[l * 8];
    *(float4*)&qv[4] = *(const float4*)&qs[l * 8 + 4];
    *(float4*)&vv[0] = *(const float4*)&vs[l * 8];
    *(float4*)&vv[4] = *(const float4*)&vs[l * 8 + 4];

    // ---- phase 1: scores (wave w: s = w*16 .. w*16+15, 2-way unrolled) ----
    {
        const float4* pe = (const float4*)(EW + ((size_t)b * 256 + w * 16) * 512);
        for (int i = 0; i < 16; i += 2) {
            float4 e00 = pe[(size_t)i * 128 + 2 * l];
            float4 e01 = pe[(size_t)i * 128 + 2 * l + 1];
            float4 e10 = pe[(size_t)(i + 1) * 128 + 2 * l];
            float4 e11 = pe[(size_t)(i + 1) * 128 + 2 * l + 1];
            float a0, a1;
            a0  = vv[0] * fast_tanh(e00.x + qv[0]);
            a0 += vv[1] * fast_tanh(e00.y + qv[1]);
            a0 += vv[2] * fast_tanh(e00.z + qv[2]);
            a0 += vv[3] * fast_tanh(e00.w + qv[3]);
            a0 += vv[4] * fast_tanh(e01.x + qv[4]);
            a0 += vv[5] * fast_tanh(e01.y + qv[5]);
            a0 += vv[6] * fast_tanh(e01.z + qv[6]);
            a0 += vv[7] * fast_tanh(e01.w + qv[7]);
            a1  = vv[0] * fast_tanh(e10.x + qv[0]);
            a1 += vv[1] * fast_tanh(e10.y + qv[1]);
            a1 += vv[2] * fast_tanh(e10.z + qv[2]);
            a1 += vv[3] * fast_tanh(e10.w + qv[3]);
            a1 += vv[4] * fast_tanh(e11.x + qv[4]);
            a1 += vv[5] * fast_tanh(e11.y + qv[5]);
            a1 += vv[6] * fast_tanh(e11.z + qv[6]);
            a1 += vv[7] * fast_tanh(e11.w + qv[7]);
#pragma unroll
            for (int off = 32; off; off >>= 1) {
                a0 += __shfl_down(a0, off);
                a1 += __shfl_down(a1, off);
            }
            if (l == 0) {
                sc[w * 16 + i]     = a0;
                sc[w * 16 + i + 1] = a1;
            }
        }
    }
    __syncthreads();

    // ---- softmax over s (waves 0-3) ----
    if (tid < 256) {
        float m = sc[tid];
#pragma unroll
        for (int off = 32; off; off >>= 1) m = fmaxf(m, __shfl_down(m, off));
        if ((tid & 63) == 0) red[tid >> 6] = m;
    }
    __syncthreads();
    if (tid < 256) {
        float mx = fmaxf(fmaxf(red[0], red[1]), fmaxf(red[2], red[3]));
        float e = expf(sc[tid] - mx);
        sc[tid] = e;
        float ssum = e;
#pragma unroll
        for (int off = 32; off; off >>= 1) ssum += __shfl_down(ssum, off);
        if ((tid & 63) == 0) red[8 + (tid >> 6)] = ssum;
    }
    __syncthreads();
    const float inv = 1.0f / (red[8] + red[9] + red[10] + red[11]);

    // ---- phase 2: partial context (wave w: s = w*16 .. w*16+15) ----
    {
        float c[8];
#pragma unroll
        for (int j = 0; j < 8; j++) c[j] = 0.f;
        for (int i = 0; i < 16; i += 2) {
            int s0 = w * 16 + i;
            int s1 = s0 + 1;
            float w0 = sc[s0];
            float w1 = sc[s1];
            const float4* p0 = (const float4*)(enc + ((size_t)s0 * 256 + b) * 512);
            const float4* p1 = (const float4*)(enc + ((size_t)s1 * 256 + b) * 512);
            float4 e00 = p0[2 * l];
            float4 e01 = p0[2 * l + 1];
            float4 e10 = p1[2 * l];
            float4 e11 = p1[2 * l + 1];
            c[0] += w0 * e00.x; c[1] += w0 * e00.y;
            c[2] += w0 * e00.z; c[3] += w0 * e00.w;
            c[4] += w0 * e01.x; c[5] += w0 * e01.y;
            c[6] += w0 * e01.z; c[7] += w0 * e01.w;
            c[0] += w1 * e10.x; c[1] += w1 * e10.y;
            c[2] += w1 * e10.z; c[3] += w1 * e10.w;
            c[4] += w1 * e11.x; c[5] += w1 * e11.y;
            c[6] += w1 * e11.z; c[7] += w1 * e11.w;
        }
        float4 c0 = make_float4(c[0], c[1], c[2], c[3]);
        float4 c1 = make_float4(c[4], c[5], c[6], c[7]);
        *(float4*)&ctxp[w][l * 8]     = c0;
        *(float4*)&ctxp[w][l * 8 + 4] = c1;
    }
    __syncthreads();
    if (tid < 512) {
        float r = 0.f;
#pragma unroll
        for (int g = 0; g < 16; g++) r += ctxp[g][tid];
        ctx[b * 512 + tid] = r * inv;
    }
}

// ---------------------------------------------------------------------------
// k_h: h_out = tanh([x | ctx | h_prev] @ [W_ih | W_hh]^T + b_ih + b_hh)
// FULL K=1088 per block (no k-split, no atomics, no zeroing).
// grid (16 nblk, 16 mblk), tile 16m x 32n, BK=32, 256 threads.
// h buffers store POST-tanh state; t=0 passes h0 directly as h_prev.
// ---------------------------------------------------------------------------
__global__ __launch_bounds__(256) void k_h(
    const float* __restrict__ xin, const float* __restrict__ ctx,
    const float* __restrict__ hprev,
    const float* __restrict__ W_ih, const float* __restrict__ W_hh,
    const float* __restrict__ b_ih, const float* __restrict__ b_hh,
    float* __restrict__ hout)
{
    __shared__ float As[32][17];
    __shared__ float Bs[32][33];
    const int tid = threadIdx.x;
    const int bn = blockIdx.x * 32;
    const int bm = blockIdx.y * 16;

    const int tx = tid & 31;        // n
    const int ty = tid >> 5;        // 0..7 -> m pair
    const int sa_m = tid >> 5;      // A stage: m = sa_m + it*8, k = sa_k
    const int sa_k = tid & 31;
    const int sb_n = tid >> 3;      // B stage: n, 4 consecutive k
    const int sb_k4 = (tid & 7) * 4;

    float acc0 = 0.f, acc1 = 0.f;

    for (int kt = 0; kt < 34; kt++) {
        const int k0 = kt * 32;
        // stage A (16m x 32k): virtual [x | ctx | h_prev], coalesced along k
#pragma unroll
        for (int it = 0; it < 2; it++) {
            int m = bm + sa_m + it * 8;
            int k = k0 + sa_k;
            float v;
            if (k < 64) v = xin[m * 64 + k];
            else if (k < 576) v = ctx[m * 512 + (k - 64)];
            else v = hprev[m * 512 + (k - 576)];
            As[sa_k][sa_m + it * 8] = v;
        }
        // stage B (32n x 32k): chunk is fully W_ih (k0<576) or W_hh (k0>=576)
        {
            int n = bn + sb_n;
            int k = k0 + sb_k4;
            float4 v4;
            if (k < 576) v4 = *(const float4*)(W_ih + (size_t)n * 576 + k);
            else         v4 = *(const float4*)(W_hh + (size_t)n * 512 + (k - 576));
            Bs[sb_k4 + 0][sb_n] = v4.x;
            Bs[sb_k4 + 1][sb_n] = v4.y;
            Bs[sb_k4 + 2][sb_n] = v4.z;
            Bs[sb_k4 + 3][sb_n] = v4.w;
        }
        __syncthreads();
#pragma unroll
        for (int kk = 0; kk < 32; kk++) {
            float b = Bs[kk][tx];
            acc0 += As[kk][ty * 2] * b;
            acc1 += As[kk][ty * 2 + 1] * b;
        }
        __syncthreads();
    }
    {
        int n = bn + tx;
        float bias = b_ih[n] + b_hh[n];
        int m0 = bm + ty * 2;
        hout[(size_t)m0 * 512 + n]       = tanhf(acc0 + bias);
        hout[(size_t)(m0 + 1) * 512 + n] = tanhf(acc1 + bias);
    }
}

// ---------------------------------------------------------------------------
// k_outq: n<64: ob = h @ Wo^T ; n>=64: qpre = h @ Wa_top.  FULL K=512,
// no atomics, no tanh (h already post-tanh). grid (9 nblk, 16 mblk),
// tile 16m x 64n, BK=32, 256 threads, 4 acc/thread.
// ---------------------------------------------------------------------------
__global__ __launch_bounds__(256) void k_outq(
    const float* __restrict__ h,
    const float* __restrict__ Wo, const float* __restrict__ Wa,
    float* __restrict__ ob, float* __restrict__ qpre)
{
    __shared__ float As[32][17];
    __shared__ float Bs[32][65];
    const int tid = threadIdx.x;
    const int bn = blockIdx.x * 64;
    const int bm = blockIdx.y * 16;
    const bool is_out = (bn == 0);

    const int tx = tid & 63;        // n
    const int ty = tid >> 6;        // 0..3 -> 4 m rows
    const int sa_m = tid >> 5;
    const int sa_k = tid & 31;
    const int wo_n = tid >> 2;      // Wo path: n, 8 consecutive k
    const int wo_k8 = (tid & 3) * 8;
    const int wa_k = tid >> 3;      // Wa path: k, 8 consecutive n
    const int wa_n8 = (tid & 7) * 8;

    float acc[4] = {0.f, 0.f, 0.f, 0.f};

    for (int kt = 0; kt < 16; kt++) {
        const int k0 = kt * 32;
#pragma unroll
        for (int it = 0; it < 2; it++) {
            int m = bm + sa_m + it * 8;
            As[sa_k][sa_m + it * 8] = h[(size_t)m * 512 + k0 + sa_k];
        }
        if (is_out) {
            float4 v0 = *(const float4*)(Wo + (size_t)wo_n * 512 + k0 + wo_k8);
            float4 v1 = *(const float4*)(Wo + (size_t)wo_n * 512 + k0 + wo_k8 + 4);
            Bs[wo_k8 + 0][wo_n] = v0.x;
            Bs[wo_k8 + 1][wo_n] = v0.y;
            Bs[wo_k8 + 2][wo_n] = v0.z;
            Bs[wo_k8 + 3][wo_n] = v0.w;
            Bs[wo_k8 + 4][wo_n] = v1.x;
            Bs[wo_k8 + 5][wo_n] = v1.y;
            Bs[wo_k8 + 6][wo_n] = v1.z;
            Bs[wo_k8 + 7][wo_n] = v1.w;
        } else {
            const float* wp = Wa + (size_t)(k0 + wa_k) * 512 + (bn - 64) + wa_n8;
            float4 v0 = *(const float4*)(wp);
            float4 v1 = *(const float4*)(wp + 4);
            Bs[wa_k][wa_n8 + 0] = v0.x;
            Bs[wa_k][wa_n8 + 1] = v0.y;
            Bs[wa_k][wa_n8 + 2] = v0.z;
            Bs[wa_k][wa_n8 + 3] = v0.w;
            Bs[wa_k][wa_n8 + 4] = v1.x;
            Bs[wa_k][wa_n8 + 5] = v1.y;
            Bs[wa_k][wa_n8 + 6] = v1.z;
            Bs[wa_k][wa_n8 + 7] = v1.w;
        }
        __syncthreads();
#pragma unroll
        for (int kk = 0; kk < 32; kk++) {
            float b = Bs[kk][tx];
            acc[0] += As[kk][ty * 4 + 0] * b;
            acc[1] += As[kk][ty * 4 + 1] * b;
            acc[2] += As[kk][ty * 4 + 2] * b;
            acc[3] += As[kk][ty * 4 + 3] * b;
        }
        __syncthreads();
    }
#pragma unroll
    for (int i = 0; i < 4; i++) {
        int m = bm + ty * 4 + i;
        if (is_out) ob[m * 64 + tx] = acc[i];
        else        qpre[(size_t)m * 512 + (bn - 64) + tx] = acc[i];
    }
}

// ---------------------------------------------------------------------------
// k_argmax: final-step dout write (t=62). out = ob + bo; dout[b][n][t].
// ---------------------------------------------------------------------------
__global__ __launch_bounds__(256) void k_argmax(const float* __restrict__ ob,
                                                const float* __restrict__ bo,
                                                float* __restrict__ dout, int t,
                                                float* __restrict__ x)
{
    const int b = blockIdx.x * 4 + (threadIdx.x >> 6);
    const int l = threadIdx.x & 63;
    float v = ob[b * 64 + l] + bo[l];
    dout[(size_t)b * (OO * NSTEP) + l * NSTEP + t] = v;
    int bi = l;
    float bv = v;
#pragma unroll
    for (int off = 1; off < 64; off <<= 1) {
        float ov = __shfl_xor(bv, off);
        int oi = __shfl_xor(bi, off);
        if (ov > bv || (ov == bv && oi < bi)) { bv = ov; bi = oi; }
    }
    x[b * 64 + l] = (l == bi) ? 1.0f : 0.0f;
}

// ---------------------------------------------------------------------------
extern "C" void kernel_launch(void* const* d_in, const int* in_sizes, int n_in,
                              void* d_out, int out_size, void* d_ws, size_t ws_size,
                              hipStream_t stream)
{
    const float* sos  = (const float*)d_in[0];
    const float* h0   = (const float*)d_in[1];
    const float* enc  = (const float*)d_in[2];
    const float* Wa   = (const float*)d_in[3];
    const float* ba   = (const float*)d_in[4];
    const float* vvec = (const float*)d_in[5];
    const float* W_ih = (const float*)d_in[6];
    const float* b_ih = (const float*)d_in[7];
    const float* W_hh = (const float*)d_in[8];
    const float* b_hh = (const float*)d_in[9];
    const float* Wo   = (const float*)d_in[10];
    const float* bo   = (const float*)d_in[11];
    float* out = (float*)d_out;

    // Workspace: exactly 34,111,488 floats (136.4 MB) — the known-good budget.
    float* ws = (float*)d_ws;
    float* EW   = ws; ws += (size_t)SS * BB * HH;   // 33,554,432  [b][s][h]
    float* qpre = ws; ws += BB * HH;                // pre-bias q
    float* ctx  = ws; ws += BB * HH;
    float* hb0  = ws; ws += BB * HH;                // h (post-tanh), buf 0
    float* hb1  = ws; ws += BB * HH;                // h (post-tanh), buf 1
    float* xb   = ws; ws += BB * OO;
    float* ob   = ws; ws += BB * OO;                // pre-bias out

    // ---- Precompute ----
    k_ew_gemm<<<dim3(512, 4), 256, 0, stream>>>(enc, Wa + 512 * 512, EW);
    k_qinit<<<dim3(16, 8), 256, 0, stream>>>(h0, Wa, qpre);

    // ---- 63 decode steps (3 kernels/step; no atomics, no zeroing) ----
    for (int t = 0; t < NSTEP; t++) {
        const float* hprev = (t == 0) ? h0 : ((t & 1) ? hb0 : hb1);
        float* hcur = (t & 1) ? hb1 : hb0;
        const float* xin = (t == 0) ? sos : xb;

        // prev-step argmax/dout + attention
        k_attn<<<256, 1024, 0, stream>>>(EW, enc, qpre, ba, vvec, ctx,
                                         ob, bo, out, xb, t);

        // h = tanh([x|ctx|h_prev] @ Wcat^T + biases)   (full-K, direct write)
        k_h<<<dim3(16, 16), 256, 0, stream>>>(xin, ctx, hprev,
                                              W_ih, W_hh, b_ih, b_hh, hcur);

        // ob = h @ Wo^T ; qpre = h @ Wa_top            (full-K, direct write)
        k_outq<<<dim3(9, 16), 256, 0, stream>>>(hcur, Wo, Wa, ob, qpre);
    }

    // final step's dout (t = 62)
    k_argmax<<<64, 256, 0, stream>>>(ob, bo, out, NSTEP - 1, xb);
}